// Round 1
// baseline (137.897 us; speedup 1.0000x reference)
//
#include <hip/hip_runtime.h>
#include <math.h>

// MutualInformationLoss: binary 256x256 occupancy map -> MI -> 1 - tanh(mi).
// Structure: zero 8KB global bitmap -> per-block LDS bitmap + atomicOr merge
// -> single-block finalize. HBM-read-bound: 2 x 50.3 MB fp32 inputs.

#define NB 256
#define BM_WORDS 2048   // 65536 bins / 32 bits

__global__ void zero_bitmap_kernel(unsigned int* __restrict__ bm) {
    int i = blockIdx.x * blockDim.x + threadIdx.x;
    if (i < BM_WORDS) bm[i] = 0u;
}

__device__ __forceinline__ void set_bin(unsigned int* bm, float a, float b) {
    // Exact replica of jnp: clip(x*255, 0, 255).astype(int32) (truncation).
    float va = fminf(fmaxf(a * 255.0f, 0.0f), 255.0f);
    float vb = fminf(fmaxf(b * 255.0f, 0.0f), 255.0f);
    int bx = (int)va;
    int by = (int)vb;
    int bin = (bx << 8) | by;
    atomicOr(&bm[bin >> 5], 1u << (bin & 31));
}

__global__ __launch_bounds__(512) void hist_kernel(const float* __restrict__ x,
                                                   const float* __restrict__ y,
                                                   unsigned int* __restrict__ gbm,
                                                   int n) {
    __shared__ unsigned int bm[BM_WORDS];
    for (int k = threadIdx.x; k < BM_WORDS; k += blockDim.x) bm[k] = 0u;
    __syncthreads();

    const int n4 = n >> 2;
    const float4* __restrict__ x4 = (const float4*)x;
    const float4* __restrict__ y4 = (const float4*)y;
    const int stride = gridDim.x * blockDim.x;
    for (int i = blockIdx.x * blockDim.x + threadIdx.x; i < n4; i += stride) {
        float4 a = x4[i];
        float4 b = y4[i];
        set_bin(bm, a.x, b.x);
        set_bin(bm, a.y, b.y);
        set_bin(bm, a.z, b.z);
        set_bin(bm, a.w, b.w);
    }
    // scalar tail (n % 4)
    for (int i = (n4 << 2) + blockIdx.x * blockDim.x + threadIdx.x; i < n; i += stride) {
        set_bin(bm, x[i], y[i]);
    }
    __syncthreads();

    // Merge into global bitmap. Racy pre-read is safe: bits are monotone
    // (only ever set), so a stale read can only cause an extra atomicOr.
    for (int k = threadIdx.x; k < BM_WORDS; k += blockDim.x) {
        unsigned int v = bm[k];
        if (v) {
            unsigned int g = gbm[k];
            if (v & ~g) atomicOr(&gbm[k], v);
        }
    }
}

__global__ __launch_bounds__(256) void finalize_kernel(const unsigned int* __restrict__ gbm,
                                                       float* __restrict__ out) {
    __shared__ unsigned int w[BM_WORDS];
    __shared__ float rcs[NB];
    __shared__ float red[8];
    const int t = threadIdx.x;  // 256 threads

    for (int k = t; k < BM_WORDS; k += 256) w[k] = gbm[k];
    __syncthreads();

    // Row count for row t: words [t*8, t*8+8)
    int r = 0;
#pragma unroll
    for (int k = 0; k < 8; ++k) r += __popc(w[t * 8 + k]);
    rcs[t] = (float)r;

    // Column count for column t: bit (t&31) of word i*8 + (t>>5) over all rows i
    const int wsel = t >> 5;
    const int bsel = t & 31;
    int c = 0;
    for (int i = 0; i < NB; ++i) c += (w[i * 8 + wsel] >> bsel) & 1;
    __syncthreads();

    // Total occupied count S (integer-valued, exact in fp32); all threads compute it.
    float S = 0.0f;
    for (int i = 0; i < NB; ++i) S += rcs[i];

    // mi = sum_{occ(i,j)} h*log(h/(px_i*py_j)), h=1/S, px=rc/S, py=cc/S
    //    = -log(S) - ( sum_i rc_i*log(rc_i/S) + sum_j cc_j*log(cc_j/S) ) / S
    // (eps=1e-10 in the reference denom perturbs mi by <1e-5; negligible vs 2e-2 tol)
    float partial = 0.0f;
    if (r > 0) partial += (float)r * logf((float)r / S);
    if (c > 0) partial += (float)c * logf((float)c / S);

    // reduce over 4 waves
    for (int off = 32; off > 0; off >>= 1) partial += __shfl_down(partial, off, 64);
    if ((t & 63) == 0) red[t >> 6] = partial;
    __syncthreads();
    if (t == 0) {
        float B = red[0] + red[1] + red[2] + red[3];
        float mi = -logf(S) - B / S;
        out[0] = 1.0f - tanhf(mi);
    }
}

extern "C" void kernel_launch(void* const* d_in, const int* in_sizes, int n_in,
                              void* d_out, int out_size, void* d_ws, size_t ws_size,
                              hipStream_t stream) {
    const float* x = (const float*)d_in[0];  // I_complementary -> row bins
    const float* y = (const float*)d_in[1];  // I_target        -> col bins
    float* out = (float*)d_out;
    unsigned int* gbm = (unsigned int*)d_ws;  // 8 KB bitmap
    const int n = in_sizes[0];

    zero_bitmap_kernel<<<(BM_WORDS + 255) / 256, 256, 0, stream>>>(gbm);
    hist_kernel<<<512, 512, 0, stream>>>(x, y, gbm, n);
    finalize_kernel<<<1, 256, 0, stream>>>(gbm, out);
}